// Round 2
// baseline (107.387 us; speedup 1.0000x reference)
//
#include <hip/hip_runtime.h>
#include <math.h>

#define VOCABSZ 100000
#define EDIM 128
#define BB 256
#define SS 512
#define NWAVE 16
#define TPW (SS / NWAVE)   // 32 tokens per wave

__global__ __launch_bounds__(NWAVE * 64)
void fused_embed_attn_kernel(const int* __restrict__ x,
                             const float* __restrict__ emb,
                             const float* __restrict__ Wq,
                             const float* __restrict__ bq,
                             const float* __restrict__ Wm,
                             const float* __restrict__ bm,
                             float* __restrict__ out)
{
    const int b    = blockIdx.x;
    const int tid  = threadIdx.x;
    const int wave = tid >> 6;
    const int lane = tid & 63;

    // Per-lane slice of Wq (lane i owns dims 2i, 2i+1)
    const float2 wq  = *reinterpret_cast<const float2*>(Wq + 2 * lane);
    const float  bq0 = bq[0];

    // Preload this wave's 32 token indices into lanes 0..31
    int idxv = 0;
    if (lane < TPW) idxv = x[b * SS + wave * TPW + lane];

    // Online-softmax state (acc distributed: lane i holds dims 2i, 2i+1)
    float m = -INFINITY;
    float Z = 0.0f;
    float accx = 0.0f, accy = 0.0f;

    #pragma unroll 4
    for (int t = 0; t < TPW; ++t) {
        const int idx = __shfl(idxv, t);
        const float2 e2 = *reinterpret_cast<const float2*>(
            emb + (size_t)idx * EDIM + 2 * lane);

        float q = e2.x * wq.x + e2.y * wq.y;   // partial dot(e, Wq)
        float s = e2.x + e2.y;                 // partial sum(e)
        #pragma unroll
        for (int off = 32; off >= 1; off >>= 1) {
            q += __shfl_xor(q, off);
            s += __shfl_xor(s, off);
        }
        const float lp = (q + bq0) * s;        // log_p for this token

        // Online softmax update
        const float mn    = fmaxf(m, lp);
        const float alpha = __expf(m - mn);    // m=-inf first iter -> 0
        const float w     = __expf(lp - mn);
        Z    = Z * alpha + w;
        accx = accx * alpha + w * e2.x;
        accy = accy * alpha + w * e2.y;
        m = mn;
    }

    // ---- combine the 16 waves' (m, Z, acc) ----
    __shared__ float sm[NWAVE];
    __shared__ float sz[NWAVE];
    __shared__ float sacc[NWAVE][EDIM];
    __shared__ float th[EDIM];

    sacc[wave][2 * lane]     = accx;
    sacc[wave][2 * lane + 1] = accy;
    if (lane == 0) { sm[wave] = m; sz[wave] = Z; }
    __syncthreads();

    if (tid < EDIM) {
        float M = sm[0];
        #pragma unroll
        for (int w = 1; w < NWAVE; ++w) M = fmaxf(M, sm[w]);
        float zt = 0.0f, tv = 0.0f;
        #pragma unroll
        for (int w = 0; w < NWAVE; ++w) {
            const float sc = __expf(sm[w] - M);
            zt += sz[w] * sc;
            tv += sacc[w][tid] * sc;
        }
        th[tid] = tv / zt;                     // t_hat[b][tid]
    }
    __syncthreads();

    // ---- final projection [128] x [128,2] + bias + relu, one wave ----
    if (tid < 64) {
        const float t0 = th[2 * tid];
        const float t1 = th[2 * tid + 1];
        const float4 wm = *reinterpret_cast<const float4*>(Wm + 4 * tid);
        float c0 = t0 * wm.x + t1 * wm.z;
        float c1 = t0 * wm.y + t1 * wm.w;
        #pragma unroll
        for (int off = 32; off >= 1; off >>= 1) {
            c0 += __shfl_xor(c0, off);
            c1 += __shfl_xor(c1, off);
        }
        if (tid == 0) {
            out[b * 2 + 0] = fmaxf(c0 + bm[0], 0.0f);
            out[b * 2 + 1] = fmaxf(c1 + bm[1], 0.0f);
        }
    }
}

extern "C" void kernel_launch(void* const* d_in, const int* in_sizes, int n_in,
                              void* d_out, int out_size, void* d_ws, size_t ws_size,
                              hipStream_t stream) {
    const int*   x   = (const int*)  d_in[0];
    const float* emb = (const float*)d_in[1];
    const float* Wq  = (const float*)d_in[2];
    const float* bq  = (const float*)d_in[3];
    const float* Wm  = (const float*)d_in[4];
    const float* bm  = (const float*)d_in[5];
    float* out = (float*)d_out;

    hipLaunchKernelGGL(fused_embed_attn_kernel, dim3(BB), dim3(NWAVE * 64), 0,
                       stream, x, emb, Wq, bq, Wm, bm, out);
}

// Round 3
// 97.244 us; speedup vs baseline: 1.1043x; 1.1043x over previous
//
#include <hip/hip_runtime.h>
#include <math.h>

#define EDIM 128
#define BB   256
#define SS   512
#define NWAVE 16
#define BLOCK (NWAVE * 64)

// DPP-based add: runs on VALU, keeps the DS pipe free.
template<int CTRL>
__device__ __forceinline__ float dpp_add(float v) {
    int r = __builtin_amdgcn_update_dpp(0, __float_as_int(v), CTRL, 0xF, 0xF, true);
    return v + __int_as_float(r);
}

// Sum across the 16 lanes of a DPP row (all 16 lanes get the total).
__device__ __forceinline__ float rowsum16(float v) {
    v = dpp_add<0xB1>(v);    // quad_perm [1,0,3,2]  (xor 1)
    v = dpp_add<0x4E>(v);    // quad_perm [2,3,0,1]  (xor 2)
    v = dpp_add<0x124>(v);   // row_ror:4
    v = dpp_add<0x128>(v);   // row_ror:8
    return v;
}

__global__ __launch_bounds__(BLOCK)
void fused_embed_attn_kernel(const int* __restrict__ x,
                             const float* __restrict__ emb,
                             const float* __restrict__ Wq,
                             const float* __restrict__ bq,
                             const float* __restrict__ Wm,
                             const float* __restrict__ bm,
                             float* __restrict__ out)
{
    const int b    = blockIdx.x;
    const int tid  = threadIdx.x;
    const int wave = tid >> 6;
    const int lane = tid & 63;
    const int row  = lane >> 4;   // 4 token-groups (DPP rows) per wave
    const int slot = lane & 15;   // 16 lanes per token
    const int d0   = slot * 8;    // 8 dims per lane

    const float4 wq0 = *reinterpret_cast<const float4*>(Wq + d0);
    const float4 wq1 = *reinterpret_cast<const float4*>(Wq + d0 + 4);
    const float  bq0 = bq[0];

    // This lane's group owns 8 consecutive tokens; indices via two int4 loads
    // (16 lanes of a group read the same 32 B -> cache broadcast).
    const int tbase = b * SS + wave * 32 + row * 8;
    const int4 ia = *reinterpret_cast<const int4*>(x + tbase);
    const int4 ib = *reinterpret_cast<const int4*>(x + tbase + 4);
    const int idx[8] = {ia.x, ia.y, ia.z, ia.w, ib.x, ib.y, ib.z, ib.w};

    // Online-softmax state, per 16-lane row (uniform within row).
    float m = -INFINITY, Z = 0.f;
    float acc[8] = {0.f, 0.f, 0.f, 0.f, 0.f, 0.f, 0.f, 0.f};

    #pragma unroll
    for (int i = 0; i < 8; ++i) {
        const float* rp = emb + (size_t)idx[i] * EDIM + d0;
        const float4 e0 = *reinterpret_cast<const float4*>(rp);
        const float4 e1 = *reinterpret_cast<const float4*>(rp + 4);

        float q = e0.x * wq0.x + e0.y * wq0.y + e0.z * wq0.z + e0.w * wq0.w
                + e1.x * wq1.x + e1.y * wq1.y + e1.z * wq1.z + e1.w * wq1.w;
        float s = e0.x + e0.y + e0.z + e0.w + e1.x + e1.y + e1.z + e1.w;
        q = rowsum16(q);                   // VALU DPP, no DS traffic
        s = rowsum16(s);
        const float lp = (q + bq0) * s;

        const float mn = fmaxf(m, lp);
        const float al = __expf(m - mn);   // m=-inf first iter -> 0
        const float w  = __expf(lp - mn);
        Z = Z * al + w;
        acc[0] = acc[0] * al + w * e0.x;  acc[1] = acc[1] * al + w * e0.y;
        acc[2] = acc[2] * al + w * e0.z;  acc[3] = acc[3] * al + w * e0.w;
        acc[4] = acc[4] * al + w * e1.x;  acc[5] = acc[5] * al + w * e1.y;
        acc[6] = acc[6] * al + w * e1.z;  acc[7] = acc[7] * al + w * e1.w;
        m = mn;
    }

    // ---- merge the wave's 4 row-groups (cross-row -> shuffles, once) ----
    float m1 = fmaxf(m, __shfl_xor(m, 16));
    const float M  = fmaxf(m1, __shfl_xor(m1, 32));
    const float sc = __expf(m - M);
    float Zs = Z * sc;
    Zs += __shfl_xor(Zs, 16);
    Zs += __shfl_xor(Zs, 32);
    #pragma unroll
    for (int j = 0; j < 8; ++j) {
        float a = acc[j] * sc;
        a += __shfl_xor(a, 16);
        a += __shfl_xor(a, 32);
        acc[j] = a;
    }

    // ---- block-level merge of the 16 wave partials ----
    __shared__ float sm[NWAVE];
    __shared__ float szv[NWAVE];
    __shared__ float sacc[NWAVE][EDIM];

    if (row == 0) {
        *reinterpret_cast<float4*>(&sacc[wave][d0])     = make_float4(acc[0], acc[1], acc[2], acc[3]);
        *reinterpret_cast<float4*>(&sacc[wave][d0 + 4]) = make_float4(acc[4], acc[5], acc[6], acc[7]);
        if (slot == 0) { sm[wave] = M; szv[wave] = Zs; }
    }
    __syncthreads();

    // wave 0: combine partials, project [128]x[128,2], relu, store
    if (tid < 64) {
        float Mb = sm[0];
        #pragma unroll
        for (int w = 1; w < NWAVE; ++w) Mb = fmaxf(Mb, sm[w]);
        float zt = 0.f, tv0 = 0.f, tv1 = 0.f;
        #pragma unroll
        for (int w = 0; w < NWAVE; ++w) {
            const float s2 = __expf(sm[w] - Mb);
            zt += szv[w] * s2;
            const float2 a2 = *reinterpret_cast<const float2*>(&sacc[w][2 * tid]);
            tv0 += a2.x * s2;
            tv1 += a2.y * s2;
        }
        const float t0 = tv0 / zt, t1 = tv1 / zt;   // t_hat dims 2*tid, 2*tid+1
        const float4 wm = *reinterpret_cast<const float4*>(Wm + 4 * tid);
        float c0 = t0 * wm.x + t1 * wm.z;
        float c1 = t0 * wm.y + t1 * wm.w;
        #pragma unroll
        for (int off = 32; off >= 1; off >>= 1) {
            c0 += __shfl_xor(c0, off);
            c1 += __shfl_xor(c1, off);
        }
        if (tid == 0) {
            out[b * 2 + 0] = fmaxf(c0 + bm[0], 0.f);
            out[b * 2 + 1] = fmaxf(c1 + bm[1], 0.f);
        }
    }
}

extern "C" void kernel_launch(void* const* d_in, const int* in_sizes, int n_in,
                              void* d_out, int out_size, void* d_ws, size_t ws_size,
                              hipStream_t stream) {
    const int*   x   = (const int*)  d_in[0];
    const float* emb = (const float*)d_in[1];
    const float* Wq  = (const float*)d_in[2];
    const float* bq  = (const float*)d_in[3];
    const float* Wm  = (const float*)d_in[4];
    const float* bm  = (const float*)d_in[5];
    float* out = (float*)d_out;

    hipLaunchKernelGGL(fused_embed_attn_kernel, dim3(BB), dim3(BLOCK), 0,
                       stream, x, emb, Wq, bq, Wm, bm, out);
}

// Round 4
// 96.707 us; speedup vs baseline: 1.1104x; 1.0055x over previous
//
#include <hip/hip_runtime.h>
#include <math.h>

#define EDIM 128
#define BB   256
#define SS   512
#define NWAVE 16
#define BLOCK (NWAVE * 64)

// DPP-based add: runs on VALU, keeps the DS pipe free.
template<int CTRL>
__device__ __forceinline__ float dpp_add(float v) {
    int r = __builtin_amdgcn_update_dpp(0, __float_as_int(v), CTRL, 0xF, 0xF, true);
    return v + __int_as_float(r);
}

// Sum across the 16 lanes of a DPP row (all 16 lanes get the total).
__device__ __forceinline__ float rowsum16(float v) {
    v = dpp_add<0xB1>(v);    // quad_perm [1,0,3,2]  (xor 1)
    v = dpp_add<0x4E>(v);    // quad_perm [2,3,0,1]  (xor 2)
    v = dpp_add<0x124>(v);   // row_ror:4
    v = dpp_add<0x128>(v);   // row_ror:8
    return v;
}

__global__ __launch_bounds__(BLOCK)
void fused_embed_attn_kernel(const int* __restrict__ x,
                             const float* __restrict__ emb,
                             const float* __restrict__ Wq,
                             const float* __restrict__ bq,
                             const float* __restrict__ Wm,
                             const float* __restrict__ bm,
                             float* __restrict__ out)
{
    const int b    = blockIdx.x;
    const int tid  = threadIdx.x;
    const int wave = tid >> 6;
    const int lane = tid & 63;
    const int row  = lane >> 4;   // 4 token-groups (DPP rows) per wave
    const int slot = lane & 15;   // 16 lanes per token
    const int d0   = slot * 8;    // 8 dims per lane

    const float4 wq0 = *reinterpret_cast<const float4*>(Wq + d0);
    const float4 wq1 = *reinterpret_cast<const float4*>(Wq + d0 + 4);
    const float  bq0 = bq[0];

    // This lane's group owns 8 consecutive tokens.
    const int tbase = b * SS + wave * 32 + row * 8;
    const int4 ia = *reinterpret_cast<const int4*>(x + tbase);
    const int4 ib = *reinterpret_cast<const int4*>(x + tbase + 4);
    const int idx[8] = {ia.x, ia.y, ia.z, ia.w, ib.x, ib.y, ib.z, ib.w};

    // ---- issue ALL gather loads up front: 16 outstanding float4s/lane ----
    float4 e0[8], e1[8];
    #pragma unroll
    for (int i = 0; i < 8; ++i) {
        const float* rp = emb + (size_t)idx[i] * EDIM + d0;
        e0[i] = *reinterpret_cast<const float4*>(rp);
        e1[i] = *reinterpret_cast<const float4*>(rp + 4);
    }

    // Online-softmax state, per 16-lane row (uniform within row).
    float m = -INFINITY, Z = 0.f;
    float acc[8] = {0.f, 0.f, 0.f, 0.f, 0.f, 0.f, 0.f, 0.f};

    #pragma unroll
    for (int i = 0; i < 8; ++i) {
        float q = e0[i].x * wq0.x + e0[i].y * wq0.y + e0[i].z * wq0.z + e0[i].w * wq0.w
                + e1[i].x * wq1.x + e1[i].y * wq1.y + e1[i].z * wq1.z + e1[i].w * wq1.w;
        float s = e0[i].x + e0[i].y + e0[i].z + e0[i].w
                + e1[i].x + e1[i].y + e1[i].z + e1[i].w;
        q = rowsum16(q);                   // VALU DPP, no DS traffic
        s = rowsum16(s);
        const float lp = (q + bq0) * s;

        const float mn = fmaxf(m, lp);
        const float al = __expf(m - mn);   // m=-inf first iter -> 0
        const float w  = __expf(lp - mn);
        Z = Z * al + w;
        acc[0] = acc[0] * al + w * e0[i].x;  acc[1] = acc[1] * al + w * e0[i].y;
        acc[2] = acc[2] * al + w * e0[i].z;  acc[3] = acc[3] * al + w * e0[i].w;
        acc[4] = acc[4] * al + w * e1[i].x;  acc[5] = acc[5] * al + w * e1[i].y;
        acc[6] = acc[6] * al + w * e1[i].z;  acc[7] = acc[7] * al + w * e1[i].w;
        m = mn;
    }

    // ---- merge the wave's 4 row-groups (cross-row -> shuffles, once) ----
    float m1 = fmaxf(m, __shfl_xor(m, 16));
    const float M  = fmaxf(m1, __shfl_xor(m1, 32));
    const float sc = __expf(m - M);
    float Zs = Z * sc;
    Zs += __shfl_xor(Zs, 16);
    Zs += __shfl_xor(Zs, 32);
    #pragma unroll
    for (int j = 0; j < 8; ++j) {
        float a = acc[j] * sc;
        a += __shfl_xor(a, 16);
        a += __shfl_xor(a, 32);
        acc[j] = a;
    }

    // ---- block-level merge of the 16 wave partials ----
    __shared__ float sm[NWAVE];
    __shared__ float szv[NWAVE];
    __shared__ float sacc[NWAVE][EDIM];

    if (row == 0) {
        *reinterpret_cast<float4*>(&sacc[wave][d0])     = make_float4(acc[0], acc[1], acc[2], acc[3]);
        *reinterpret_cast<float4*>(&sacc[wave][d0 + 4]) = make_float4(acc[4], acc[5], acc[6], acc[7]);
        if (slot == 0) { sm[wave] = M; szv[wave] = Zs; }
    }
    __syncthreads();

    // wave 0: combine partials, project [128]x[128,2], relu, store
    if (tid < 64) {
        float Mb = sm[0];
        #pragma unroll
        for (int w = 1; w < NWAVE; ++w) Mb = fmaxf(Mb, sm[w]);
        float zt = 0.f, tv0 = 0.f, tv1 = 0.f;
        #pragma unroll
        for (int w = 0; w < NWAVE; ++w) {
            const float s2 = __expf(sm[w] - Mb);
            zt += szv[w] * s2;
            const float2 a2 = *reinterpret_cast<const float2*>(&sacc[w][2 * tid]);
            tv0 += a2.x * s2;
            tv1 += a2.y * s2;
        }
        const float t0 = tv0 / zt, t1 = tv1 / zt;   // t_hat dims 2*tid, 2*tid+1
        const float4 wm = *reinterpret_cast<const float4*>(Wm + 4 * tid);
        float c0 = t0 * wm.x + t1 * wm.z;
        float c1 = t0 * wm.y + t1 * wm.w;
        #pragma unroll
        for (int off = 32; off >= 1; off >>= 1) {
            c0 += __shfl_xor(c0, off);
            c1 += __shfl_xor(c1, off);
        }
        if (tid == 0) {
            out[b * 2 + 0] = fmaxf(c0 + bm[0], 0.f);
            out[b * 2 + 1] = fmaxf(c1 + bm[1], 0.f);
        }
    }
}

extern "C" void kernel_launch(void* const* d_in, const int* in_sizes, int n_in,
                              void* d_out, int out_size, void* d_ws, size_t ws_size,
                              hipStream_t stream) {
    const int*   x   = (const int*)  d_in[0];
    const float* emb = (const float*)d_in[1];
    const float* Wq  = (const float*)d_in[2];
    const float* bq  = (const float*)d_in[3];
    const float* Wm  = (const float*)d_in[4];
    const float* bm  = (const float*)d_in[5];
    float* out = (float*)d_out;

    hipLaunchKernelGGL(fused_embed_attn_kernel, dim3(BB), dim3(BLOCK), 0,
                       stream, x, emb, Wq, bq, Wm, bm, out);
}